// Round 13
// baseline (47.911 us; speedup 1.0000x reference)
//
#include <hip/hip_runtime.h>
#include <hip/hip_bf16.h>

// NF4 double-quant dequantize + x @ W^T — counted-vmcnt pipeline (T3/T4).
// packed raw -> LDS via global_load_lds (tri-buffer), raw s_barrier + asm
// vmcnt(1): next chunk's load stays in flight across every barrier (never
// drain to 0 mid-loop — the r7-r12 ceiling was the __syncthreads vmcnt(0)).
// Dequant at fragment-read time (LDS->reg). x bf16 in LDS (staged once,
// XOR-swizzled). Scales precomputed as {cs,noc} (pre-kernel), reg-prefetched.
// KSPLIT=8 -> partials in ws + fixed-order reduce (deterministic, no atomics).

#define OUT_D 14336
#define IN_D  4096
#define B_D   32
#define KSPLIT 8
#define KRANGE (IN_D / KSPLIT)       // 512 elems per block
#define KC 64                        // elems per chunk (= 1 scale block)
#define CHUNKS (KRANGE / KC)         // 8
#define NB (OUT_D * IN_D / 64)       // 917504
#define SZ_X (B_D * IN_D)            // 131072

typedef __attribute__((ext_vector_type(4))) float f32x4;
typedef __attribute__((ext_vector_type(2))) float f32x2;
typedef __attribute__((ext_vector_type(4))) int   i32x4;
typedef __bf16 bf16x8 __attribute__((ext_vector_type(8)));
using u16 = unsigned short;

typedef const __attribute__((address_space(1))) void* gas1_t;
typedef __attribute__((address_space(3))) void* las3_t;

__device__ __forceinline__ void gll16(const void* g, void* l) {
    __builtin_amdgcn_global_load_lds((gas1_t)g, (las3_t)l, 16, 0, 0);
}

// pre: csnoc pairs for all NB blocks + x f32->bf16
__global__ __launch_bounds__(256) void pre_kernel(
    const float* __restrict__ x,
    const float* __restrict__ absmax, const float* __restrict__ code,
    const float* __restrict__ offset,
    const float* __restrict__ g_absmax, const float* __restrict__ g_code,
    u16* __restrict__ xb, f32x2* __restrict__ csn)
{
    const int i = blockIdx.x * 256 + threadIdx.x;   // < NB (grid exact)
    float am = absmax[i], cd = code[i], of = offset[i];
    float ga = g_absmax[i >> 2], gc = g_code[i >> 2];
    float cs = (am * ga) / (cd * gc);
    f32x2 v; v.x = cs; v.y = -of * cs;
    csn[i] = v;
    if (i < SZ_X) {
        __bf16 h = (__bf16)x[i];
        xb[i] = __builtin_bit_cast(u16, h);
    }
}

__global__ __launch_bounds__(256, 3) void nf4_main(
    const u16* __restrict__ xb,       // [32][4096] bf16
    const int* __restrict__ packed,   // [N/2] raw words
    const f32x2* __restrict__ csn,    // [NB] {cs, noc}
    float* __restrict__ part)         // [KSPLIT][32][14336]
{
    __shared__ u16 xs[B_D][512];      // 32 KB swizzled bf16 x slice
    __shared__ int wb[3][32][32];     // 12 KB raw packed, tri-buffered

    const int t      = threadIdx.x;
    const int o_base = blockIdx.x * 32;
    const int kz     = blockIdx.y;

    const int wave = t >> 6, lane = t & 63;
    const int m_base = (wave & 1) * 16, n_base = (wave >> 1) * 16;
    const int frow = lane & 15, q = lane >> 4;
    const int rown = n_base + frow;      // W row (B-frag + dequant + scales)
    const int rowa = m_base + frow;      // batch row (A-frag)

    // ---- stage x slice (once): swizzled write, reg-staged ----
    #pragma unroll
    for (int j = 0; j < 8; ++j) {
        int slot = t + j * 256;
        int r = slot >> 6, c = slot & 63;
        bf16x8 v = *reinterpret_cast<const bf16x8*>(xb + r * IN_D + kz * KRANGE + c * 8);
        *reinterpret_cast<bf16x8*>(&xs[r][(c ^ (r & 7)) * 8]) = v;
    }

    // ---- scale prefetch: this lane's 8 {cs,noc} pairs (64B contiguous) ----
    f32x4 scp[4];
    {
        const f32x4* sp = reinterpret_cast<const f32x4*>(
            csn + (o_base + rown) * 64 + kz * CHUNKS);
        scp[0] = sp[0]; scp[1] = sp[1]; scp[2] = sp[2]; scp[3] = sp[3];
    }
    __builtin_amdgcn_sched_barrier(0);   // pin: scale loads older than gll

    // ---- gll source addressing (pre-swizzled global col, rule #21) ----
    const int srow = t >> 3;                      // 0..31 (8 slots/row)
    const int scol = (t & 7) ^ (srow & 7);        // swizzled 16B-col
    const int* gsrc = packed + (o_base + srow) * (IN_D / 2)
                             + kz * (KRANGE / 2) + scol * 4;

    // prologue: chunks 0,1 in flight
    gll16(gsrc + 0 * 32, &wb[0][wave * 8][0]);
    gll16(gsrc + 1 * 32, &wb[1][wave * 8][0]);

    f32x4 acc = {0.f, 0.f, 0.f, 0.f};

    #pragma unroll
    for (int C = 0; C < CHUNKS; ++C) {
        // counted wait: chunk C ready, chunk C+1 stays in flight
        if (C == 0)               asm volatile("s_waitcnt vmcnt(1) lgkmcnt(0)" ::: "memory");
        else if (C < CHUNKS - 1)  asm volatile("s_waitcnt vmcnt(1)" ::: "memory");
        else                      asm volatile("s_waitcnt vmcnt(0)" ::: "memory");
        __builtin_amdgcn_s_barrier();
        __builtin_amdgcn_sched_barrier(0);

        // issue chunk C+2 into buffer (C+2)%3 — that buffer was last read in
        // compute(C-1), which all waves finished before this barrier: safe.
        if (C + 2 < CHUNKS)
            gll16(gsrc + (C + 2) * 32, &wb[(C + 2) % 3][wave * 8][0]);

        const int buf = C % 3;
        const float cs  = scp[C >> 1][(C & 1) * 2];
        const float noc = scp[C >> 1][(C & 1) * 2 + 1];

        #pragma unroll
        for (int s = 0; s < 2; ++s) {
            // B raw: words (s*4+q)*4..+4 of this chunk = k elems s*32+q*8..+8
            i32x4 braw = *reinterpret_cast<const i32x4*>(
                &wb[buf][rown][(((s * 4 + q) ^ (rown & 7)) * 4)]);
            // A: same k range, from swizzled x LDS
            int ca = C * 8 + s * 4 + q;
            bf16x8 a = *reinterpret_cast<const bf16x8*>(
                &xs[rowa][(ca ^ (rowa & 7)) * 8]);
            bf16x8 b;
            #pragma unroll
            for (int w = 0; w < 4; ++w) {
                int ww = braw[w];
                b[2 * w]     = (__bf16)fmaf((float)(ww & 15),        cs, noc);
                b[2 * w + 1] = (__bf16)fmaf((float)((ww >> 4) & 15), cs, noc);
            }
            acc = __builtin_amdgcn_mfma_f32_16x16x32_bf16(a, b, acc, 0, 0, 0);
        }
    }

    // ---- partial store (plain, deterministic): D col=lane&15, row=q*4+i ----
    float* pp = part + (size_t)kz * (B_D * OUT_D);
    const int oc = o_base + n_base + frow;
    const int r0 = m_base + q * 4;
    #pragma unroll
    for (int i = 0; i < 4; ++i)
        pp[(r0 + i) * OUT_D + oc] = acc[i];
}

// fixed-order reduce over KSPLIT partials (deterministic)
__global__ __launch_bounds__(256) void reduce_kernel(
    const float* __restrict__ part, float* __restrict__ out)
{
    const int i = (blockIdx.x * 256 + threadIdx.x) * 4;
    f32x4 s = *reinterpret_cast<const f32x4*>(part + i);
    #pragma unroll
    for (int k = 1; k < KSPLIT; ++k) {
        f32x4 v = *reinterpret_cast<const f32x4*>(
            part + (size_t)k * (B_D * OUT_D) + i);
        s[0] += v[0]; s[1] += v[1]; s[2] += v[2]; s[3] += v[3];
    }
    *reinterpret_cast<f32x4*>(out + i) = s;
}

extern "C" void kernel_launch(void* const* d_in, const int* in_sizes, int n_in,
                              void* d_out, int out_size, void* d_ws, size_t ws_size,
                              hipStream_t stream) {
    const void* px = nullptr;
    const void* ppk = nullptr;
    const void* trio[3] = {nullptr, nullptr, nullptr};
    const void* pair[2] = {nullptr, nullptr};
    int ntrio = 0, npair = 0;
    const int SZ_PK  = OUT_D * (IN_D / 2);
    const int SZ_NB  = NB;
    const int SZ_NG  = OUT_D * (IN_D / 256);
    for (int i = 0; i < n_in; ++i) {
        int s = in_sizes[i];
        if (s == SZ_X) px = d_in[i];
        else if (s == SZ_PK) ppk = d_in[i];
        else if (s == SZ_NB) { if (ntrio < 3) trio[ntrio++] = d_in[i]; }
        else if (s == SZ_NG) { if (npair < 2) pair[npair++] = d_in[i]; }
    }
    if (!px || !ppk || ntrio != 3 || npair != 2) {
        px = d_in[0]; ppk = d_in[1];
        trio[0] = d_in[2]; trio[1] = d_in[3]; trio[2] = d_in[4];
        pair[0] = d_in[5]; pair[1] = d_in[6];
    }

    // ws layout: xb bf16 [256KB) | csn f32x2 [7.34MB) | partials [14.7MB)
    char* ws = (char*)d_ws;
    u16*   xb   = (u16*)ws;
    f32x2* csn  = (f32x2*)(ws + 262144);
    float* part = (float*)(ws + 262144 + (size_t)NB * 8);

    pre_kernel<<<dim3(NB / 256), dim3(256), 0, stream>>>(
        (const float*)px,
        (const float*)trio[0], (const float*)trio[1], (const float*)trio[2],
        (const float*)pair[0], (const float*)pair[1],
        xb, csn);

    nf4_main<<<dim3(OUT_D / 32, KSPLIT), dim3(256), 0, stream>>>(
        xb, (const int*)ppk, csn, part);

    reduce_kernel<<<dim3(B_D * OUT_D / 4 / 256), dim3(256), 0, stream>>>(
        part, (float*)d_out);
}